// Round 15
// baseline (317.481 us; speedup 1.0000x reference)
//
#include <hip/hip_runtime.h>
#include <stdint.h>

typedef unsigned int u32;
typedef unsigned short u16;

#define NPTS 1000000
#define DIMD 500
#define DIMH 500
#define DIMW 40
#define NVOX 10000000      // DIMD*DIMH*DIMW
#define NW 312500          // NVOX/32 occupancy-bitmask words
#define MAXV 40000
#define MAXP 32
#define NTOT (MAXV * MAXP) // 1,280,000 rows in the flat MLP input
#define PCAP 65536         // compact kept-point capacity (expected ~42k)
#define OUTV (MAXV * 128)  // 5,120,000 voxel_out elements
#define WCHUNK 4096        // bitmask words per scan block
#define SNB ((NW + WCHUNK - 1) / WCHUNK) // 77 scan blocks
#define S1B 256            // stats1 grid
#define VB ((MAXV + 255) / 256)          // 157 vox-scan blocks
#define SZSEG 4            // statsZ row-segments per channel

// ---------- helpers ----------
__device__ __forceinline__ float b2f(u16 h) { return __uint_as_float(((u32)h) << 16); }

__device__ __forceinline__ u16 f2b(float f) {
    u32 u = __float_as_uint(f);
    if ((u & 0x7F800000u) == 0x7F800000u) {           // inf / nan
        u16 h = (u16)(u >> 16);
        if (u & 0x007FFFFFu) h |= 0x40;               // quiet nan
        return h;
    }
    u32 lsb = (u >> 16) & 1u;
    return (u16)((u + 0x7FFFu + lsb) >> 16);          // round-to-nearest-even
}

// dtype-adaptive element load/store. bf==true -> bf16 (u16), else f32.
__device__ __forceinline__ float ld1(const void* p, int i, bool bf) {
    return bf ? b2f(((const u16*)p)[i]) : ((const float*)p)[i];
}
__device__ __forceinline__ float4 ld4(const void* p, int i4, bool bf) {
    if (bf) {
        ushort4 q = ((const ushort4*)p)[i4];
        return make_float4(b2f(q.x), b2f(q.y), b2f(q.z), b2f(q.w));
    }
    return ((const float4*)p)[i4];
}
__device__ __forceinline__ void st1(void* p, size_t i, float v, bool bf) {
    if (bf) ((u16*)p)[i] = f2b(v);
    else ((float*)p)[i] = v;
}

// exact replica of ((xyz - RANGE_MIN)/VOXEL_SIZE).astype(int32) + validity (f32 ops)
__device__ __forceinline__ bool pkey(float x, float y, float z, int& key) {
    float fx = (x - (-50.0f)) / 0.2f;
    float fy = (y - (-50.0f)) / 0.2f;
    float fz = (z - (-3.0f)) / 0.2f;
    int ix = (int)fx, iy = (int)fy, iz = (int)fz;
    if (ix < 0 || ix >= DIMD || iy < 0 || iy >= DIMH || iz < 0 || iz >= DIMW) return false;
    key = ix * (DIMH * DIMW) + iy * DIMW + iz;
    return true;
}

// ---------- kernels ----------

// Detect input dtype (bf16 vs f32) from points' bit patterns. Also inits firstkey.
__global__ void k_detect(const void* pts, u32* dflag, int* firstkey) {
    __shared__ int s[256];
    int t = threadIdx.x;
    const u16* p = (const u16*)pts;
    int good = 0;
    for (int i = 0; i < 16; i++) {
        u16 v = p[(size_t)(t * 16 + i) * 2];
        int e = (v >> 7) & 0xFF;
        if (e >= 90 && e <= 140) good++;
    }
    s[t] = good;
    __syncthreads();
    for (int o = 128; o > 0; o >>= 1) {
        if (t < o) s[t] += s[t + o];
        __syncthreads();
    }
    if (t == 0) {
        *dflag = (s[0] >= (4096 * 3) / 5) ? 1u : 0u;
        *firstkey = 0x7FFFFFFF;
    }
}

// occupancy bitmask
__global__ void k_hist(const void* __restrict__ pts, const u32* dflag, u32* __restrict__ occ) {
    int i = blockIdx.x * 256 + threadIdx.x;
    if (i >= NPTS) return;
    bool bf = *dflag != 0;
    float4 p = ld4(pts, i, bf);
    int key;
    if (pkey(p.x, p.y, p.z, key)) atomicOr(&occ[key >> 5], 1u << (key & 31));
}

__global__ void k_scan1(const u32* __restrict__ occ, u32* bsums, int* firstkey) {
    __shared__ int s[256];
    __shared__ int sm[256];
    int t = threadIdx.x;
    int base = blockIdx.x * WCHUNK + t * 16;
    int tot = 0, mn = 0x7FFFFFFF;
    for (int i = 0; i < 16; i++) {
        int w = base + i;
        if (w < NW) {
            u32 x = occ[w];
            tot += __popc(x);
            if (x && mn == 0x7FFFFFFF) mn = w * 32 + __builtin_ctz(x);
        }
    }
    s[t] = tot; sm[t] = mn;
    __syncthreads();
    for (int o = 128; o > 0; o >>= 1) {
        if (t < o) { s[t] += s[t + o]; sm[t] = min(sm[t], sm[t + o]); }
        __syncthreads();
    }
    if (t == 0) {
        bsums[blockIdx.x] = (u32)s[0];
        if (sm[0] != 0x7FFFFFFF) atomicMin(firstkey, sm[0]);
    }
}

// per-word rank bases (only where rank can be < MAXV) + coords + fused pad.
__global__ void k_scan3(const u32* __restrict__ occ, const u32* __restrict__ bsums,
                        const int* __restrict__ firstkey, const u32* dflag,
                        u32* __restrict__ wordbase, void* __restrict__ out) {
    __shared__ int s[256];
    __shared__ u32 red[256];
    __shared__ u32 sboff, stot;
    int t = threadIdx.x;
    bool bf = *dflag != 0;
    red[t] = (t < (int)SNB && t < (int)blockIdx.x) ? bsums[t] : 0u;
    __syncthreads();
    for (int o = 128; o > 0; o >>= 1) {
        if (t < o) red[t] += red[t + o];
        __syncthreads();
    }
    if (t == 0) sboff = red[0];
    __syncthreads();
    if (blockIdx.x == 0) {                      // total occupied (for pad path)
        red[t] = (t < (int)SNB) ? bsums[t] : 0u;
        __syncthreads();
        for (int o = 128; o > 0; o >>= 1) {
            if (t < o) red[t] += red[t + o];
            __syncthreads();
        }
        if (t == 0) stot = red[0];
        __syncthreads();
    }
    u32 boff = sboff;
    if (blockIdx.x != 0 && boff >= (u32)MAXV) return;  // nothing to write here
    int base = blockIdx.x * WCHUNK + t * 16;
    int tot = 0;
    for (int i = 0; i < 16; i++) {
        int w = base + i;
        if (w < NW) tot += __popc(occ[w]);
    }
    s[t] = tot;
    __syncthreads();
    for (int o = 1; o < 256; o <<= 1) {
        int v = (t >= o) ? s[t - o] : 0;
        __syncthreads();
        s[t] += v;
        __syncthreads();
    }
    int run = (int)boff + s[t] - tot;
    for (int i = 0; i < 16; i++) {
        if (run >= MAXV) break;
        int w = base + i;
        if (w >= NW) break;
        u32 x = occ[w];
        wordbase[w] = (u32)run;
        u32 xx = x;
        int r = run;
        while (xx) {
            int b = __builtin_ctz(xx);
            xx &= xx - 1;
            if (r < MAXV) {
                int key = w * 32 + b;
                int ix = key / 20000;
                int rem = key - ix * 20000;
                int iy = rem / 40;
                int iz = rem - iy * 40;
                size_t o4 = (size_t)OUTV + (size_t)r * 4;
                st1(out, o4 + 0, 0.0f, bf);
                st1(out, o4 + 1, (float)ix, bf);
                st1(out, o4 + 2, (float)iy, bf);
                st1(out, o4 + 3, (float)iz, bf);
            }
            r++;
        }
        run += __popc(x);
    }
    // fused pad (only if fewer than MAXV occupied voxels — rare edge case)
    if (blockIdx.x == 0) {
        int to = (int)stot;
        int fk = *firstkey;
        if (fk >= NVOX || fk < 0) fk = 0;
        int ix = fk / 20000, rem = fk - ix * 20000, iy = rem / 40, iz = rem - iy * 40;
        for (int r = to + t; r < MAXV; r += 256) {
            size_t o4 = (size_t)OUTV + (size_t)r * 4;
            st1(out, o4 + 0, 0.0f, bf);
            st1(out, o4 + 1, (float)ix, bf);
            st1(out, o4 + 2, (float)iy, bf);
            st1(out, o4 + 3, (float)iz, bf);
        }
    }
}

// single 1M-point pass with early-exit on wordbase (0xFFFFFFFF where rank >= MAXV)
__global__ void k_gather(const void* __restrict__ pts, const u32* __restrict__ occ,
                         const u32* __restrict__ wordbase, const u32* dflag,
                         u32* __restrict__ slotctr, float4* __restrict__ slotted) {
    int i = blockIdx.x * 256 + threadIdx.x;
    if (i >= NPTS) return;
    bool bf = *dflag != 0;
    float4 p = ld4(pts, i, bf);
    int key;
    if (!pkey(p.x, p.y, p.z, key)) return;
    int w = key >> 5, b = key & 31;
    u32 wb = wordbase[w];
    if (wb >= (u32)MAXV) return;               // fast path out
    int rank = (int)wb + __popc(occ[w] & ((1u << b) - 1u));
    if (rank >= MAXV) return;
    u32 slot = atomicAdd(&slotctr[rank], 1u);
    if (slot >= MAXP) return;
    slotted[(size_t)rank * MAXP + slot] = p;
}

// per-block sums of min(slotctr,32)
__global__ void k_vox1(const u32* __restrict__ slotctr, u32* __restrict__ vbsums) {
    __shared__ u32 s[256];
    int t = threadIdx.x;
    int v = blockIdx.x * 256 + t;
    u32 cnt = (v < MAXV) ? min(slotctr[v], (u32)MAXP) : 0u;
    s[t] = cnt;
    __syncthreads();
    for (int o = 128; o > 0; o >>= 1) {
        if (t < o) s[t] += s[t + o];
        __syncthreads();
    }
    if (t == 0) vbsums[blockIdx.x] = s[0];
}

// intra-block scan -> voxbase + compaction; inline vboffs reduction; block 0 writes nkept.
__global__ void k_vox3(const u32* __restrict__ slotctr, const u32* __restrict__ vbsums,
                       u32* __restrict__ voxbase, const float4* __restrict__ slotted,
                       float4* __restrict__ cpt, u32* __restrict__ nkept) {
    __shared__ u32 s[256];
    __shared__ u32 red[256];
    __shared__ u32 sboff;
    int t = threadIdx.x;
    int v = blockIdx.x * 256 + t;
    red[t] = (t < VB && t < (int)blockIdx.x) ? vbsums[t] : 0u;
    __syncthreads();
    for (int o = 128; o > 0; o >>= 1) {
        if (t < o) red[t] += red[t + o];
        __syncthreads();
    }
    if (t == 0) sboff = red[0];
    __syncthreads();
    if (blockIdx.x == 0) {
        red[t] = (t < VB) ? vbsums[t] : 0u;
        __syncthreads();
        for (int o = 128; o > 0; o >>= 1) {
            if (t < o) red[t] += red[t + o];
            __syncthreads();
        }
        if (t == 0) *nkept = red[0];
        __syncthreads();
    }
    u32 cnt = (v < MAXV) ? min(slotctr[v], (u32)MAXP) : 0u;
    s[t] = cnt;
    __syncthreads();
    for (int o = 1; o < 256; o <<= 1) {
        u32 x = (t >= o) ? s[t - o] : 0u;
        __syncthreads();
        s[t] += x;
        __syncthreads();
    }
    if (v < MAXV) {
        u32 base = sboff + s[t] - cnt;
        voxbase[v] = base;
        for (int sl = 0; sl < (int)cnt; sl++) {
            u32 p = base + sl;
            if (p < PCAP) cpt[p] = slotted[(size_t)v * MAXP + sl];
        }
    }
}

// layer-1 pre-BN stats: wave-walk over compact list, lane=channel, f64 reg accum
__global__ __launch_bounds__(256) void k_stats1(const void* __restrict__ W1, const void* __restrict__ b1,
                                                const u32* dflag, const u32* nkept,
                                                const float4* __restrict__ cpt,
                                                double* __restrict__ part1) {
    __shared__ double ls[4][64], lq[4][64];
    int t = threadIdx.x, lane = t & 63, w = t >> 6;
    bool bf = *dflag != 0;
    float w0 = ld1(W1, 0 * 64 + lane, bf);
    float w1 = ld1(W1, 1 * 64 + lane, bf);
    float w2 = ld1(W1, 2 * 64 + lane, bf);
    float w3 = ld1(W1, 3 * 64 + lane, bf);
    float bb = ld1(b1, lane, bf);
    int P = min((int)*nkept, PCAP);
    int G = gridDim.x * 4, gw = blockIdx.x * 4 + w;
    double S = 0.0, Q = 0.0;
    for (int p = gw; p < P; p += G) {
        float4 f = cpt[p];                  // wave-uniform -> broadcast
        float z = f.x * w0 + f.y * w1 + f.z * w2 + f.w * w3 + bb;
        S += (double)z;
        Q += (double)z * (double)z;
    }
    ls[w][lane] = S; lq[w][lane] = Q;
    __syncthreads();
    if (t < 64) {
        double SS = ls[0][t] + ls[1][t] + ls[2][t] + ls[3][t];
        double QQ = lq[0][t] + lq[1][t] + lq[2][t] + lq[3][t];
        part1[(size_t)blockIdx.x * 128 + t] = SS;
        part1[(size_t)blockIdx.x * 128 + 64 + t] = QQ;
    }
}

__global__ void k_fin1(const void* __restrict__ b1, const void* __restrict__ g1, const void* __restrict__ be1,
                       const void* __restrict__ W2, const void* __restrict__ b2,
                       const u32* dflag, const u32* nkept, const double* __restrict__ part1,
                       float* mu1, float* rs1, float* z2z) {
    __shared__ double accS[4][64], accQ[4][64];
    __shared__ float h1s[64];
    int t = threadIdx.x, q = t >> 6, c = t & 63; // 256 threads
    bool bf = *dflag != 0;
    double S = 0.0, Q = 0.0;
    for (int b = q; b < S1B; b += 4) {
        S += part1[(size_t)b * 128 + c];
        Q += part1[(size_t)b * 128 + 64 + c];
    }
    accS[q][c] = S; accQ[q][c] = Q;
    __syncthreads();
    if (t < 64) {
        S = accS[0][t] + accS[1][t] + accS[2][t] + accS[3][t];
        Q = accQ[0][t] + accQ[1][t] + accQ[2][t] + accQ[3][t];
        int P = min((int)*nkept, PCAP);
        double Zn = (double)(NTOT - P);
        double bb = (double)ld1(b1, t, bf);
        double mu = (S + Zn * bb) / (double)NTOT;
        double var = (Q + Zn * bb * bb) / (double)NTOT - mu * mu;
        if (var < 0.0) var = 0.0;
        float rs = (float)(1.0 / sqrt(var + 1e-5));
        float muf = (float)mu;
        mu1[t] = muf;
        rs1[t] = rs;
        float h = ((float)bb - muf) * rs * ld1(g1, t, bf) + ld1(be1, t, bf);
        h1s[t] = h > 0.f ? h : 0.f;
    }
    __syncthreads();
    if (t < 64) {
        float acc = ld1(b2, t, bf);
        for (int j = 0; j < 64; j++) acc += h1s[j] * ld1(W2, j * 64 + t, bf);
        z2z[t] = acc;
    }
}

// 2 points/thread, 32-channel group per block: h1 in regs, broadcast weight reads.
// z2buf column-major bf16 (coalesced, half traffic).
__global__ __launch_bounds__(256, 2) void k_passZ2(const void* __restrict__ W1, const void* __restrict__ b1,
                                                   const void* __restrict__ g1, const void* __restrict__ be1,
                                                   const void* __restrict__ W2, const void* __restrict__ b2,
                                                   const u32* dflag, const u32* nkept,
                                                   const float* __restrict__ mu1, const float* __restrict__ rs1,
                                                   const float4* __restrict__ cpt,
                                                   u16* __restrict__ z2b) {
    __shared__ __align__(16) float w2L[32][68];  // w2L[cl][j] = W2[j][c0+cl]
    __shared__ __align__(16) float sW1[4][64];
    __shared__ __align__(16) float aB1[64], aK1[64], aC1[64], aB2g[32];
    int t = threadIdx.x;
    int pb = blockIdx.x >> 1, cg = blockIdx.x & 1;
    int c0 = cg * 32;
    bool bf = *dflag != 0;
    for (int idx = t; idx < 2048; idx += 256) {
        int j = idx & 63, cl = idx >> 6;         // j-fastest -> conflict-free LDS writes
        w2L[cl][j] = ld1(W2, j * 64 + c0 + cl, bf);
    }
    if (t < 64) {
        sW1[0][t] = ld1(W1, t, bf);
        sW1[1][t] = ld1(W1, 64 + t, bf);
        sW1[2][t] = ld1(W1, 128 + t, bf);
        sW1[3][t] = ld1(W1, 192 + t, bf);
        aB1[t] = ld1(b1, t, bf);
        float k1 = rs1[t] * ld1(g1, t, bf);
        aK1[t] = k1;
        aC1[t] = ld1(be1, t, bf) - mu1[t] * k1;
    }
    if (t < 32) aB2g[t] = ld1(b2, c0 + t, bf);
    __syncthreads();
    int NK = min((int)*nkept, PCAP);
    int i = pb * 512 + t;
    int i2 = i + 256;
    if (i >= NK) return;
    bool has2 = i2 < NK;
    float4 f0 = cpt[i];
    float4 f1 = cpt[has2 ? i2 : i];
    float4 h0[16], h1[16];
    #pragma unroll
    for (int qq = 0; qq < 16; qq++) {
        float4 a = *(const float4*)&sW1[0][4 * qq];
        float4 b = *(const float4*)&sW1[1][4 * qq];
        float4 cc = *(const float4*)&sW1[2][4 * qq];
        float4 d = *(const float4*)&sW1[3][4 * qq];
        float4 bb = *(const float4*)&aB1[4 * qq];
        float4 kk = *(const float4*)&aK1[4 * qq];
        float4 c1 = *(const float4*)&aC1[4 * qq];
        float4 z;
        z.x = f0.x * a.x + f0.y * b.x + f0.z * cc.x + f0.w * d.x + bb.x;
        z.y = f0.x * a.y + f0.y * b.y + f0.z * cc.y + f0.w * d.y + bb.y;
        z.z = f0.x * a.z + f0.y * b.z + f0.z * cc.z + f0.w * d.z + bb.z;
        z.w = f0.x * a.w + f0.y * b.w + f0.z * cc.w + f0.w * d.w + bb.w;
        h0[qq] = make_float4(fmaxf(z.x * kk.x + c1.x, 0.f), fmaxf(z.y * kk.y + c1.y, 0.f),
                             fmaxf(z.z * kk.z + c1.z, 0.f), fmaxf(z.w * kk.w + c1.w, 0.f));
        z.x = f1.x * a.x + f1.y * b.x + f1.z * cc.x + f1.w * d.x + bb.x;
        z.y = f1.x * a.y + f1.y * b.y + f1.z * cc.y + f1.w * d.y + bb.y;
        z.z = f1.x * a.z + f1.y * b.z + f1.z * cc.z + f1.w * d.z + bb.z;
        z.w = f1.x * a.w + f1.y * b.w + f1.z * cc.w + f1.w * d.w + bb.w;
        h1[qq] = make_float4(fmaxf(z.x * kk.x + c1.x, 0.f), fmaxf(z.y * kk.y + c1.y, 0.f),
                             fmaxf(z.z * kk.z + c1.z, 0.f), fmaxf(z.w * kk.w + c1.w, 0.f));
    }
    for (int cl = 0; cl < 32; cl++) {
        float a0 = aB2g[cl], a1 = a0;
        #pragma unroll
        for (int qq = 0; qq < 16; qq++) {
            float4 wv = *(const float4*)&w2L[cl][4 * qq];
            a0 += h0[qq].x * wv.x + h0[qq].y * wv.y + h0[qq].z * wv.z + h0[qq].w * wv.w;
            a1 += h1[qq].x * wv.x + h1[qq].y * wv.y + h1[qq].z * wv.z + h1[qq].w * wv.w;
        }
        size_t cb = (size_t)(c0 + cl) * PCAP;
        z2b[cb + i] = f2b(a0);                 // lanes consecutive -> coalesced
        if (has2) z2b[cb + i2] = f2b(a1);
    }
}

// per-(channel,segment) column sum/sumsq of z2b: 256 blocks, 16B vector loads
__global__ __launch_bounds__(256) void k_statsZ(const u16* __restrict__ z2b, const u32* nkept,
                                                double* __restrict__ part2c) {
    __shared__ double sS[256], sQ[256];
    int c = blockIdx.x & 63, seg = blockIdx.x >> 6;
    int t = threadIdx.x;
    int NK = min((int)*nkept, PCAP);
    int nvec = (NK + 7) >> 3;                 // # of 8-elem (16B) vectors
    int per = (nvec + SZSEG - 1) / SZSEG;
    int lo = seg * per, hi = min(lo + per, nvec);
    const uint4* col = (const uint4*)(z2b + (size_t)c * PCAP); // 16B-aligned
    double S = 0.0, Q = 0.0;
    for (int iv = lo + t; iv < hi; iv += 256) {
        uint4 q = col[iv];
        int base = iv * 8;
        float x[8];
        x[0] = b2f((u16)q.x); x[1] = b2f((u16)(q.x >> 16));
        x[2] = b2f((u16)q.y); x[3] = b2f((u16)(q.y >> 16));
        x[4] = b2f((u16)q.z); x[5] = b2f((u16)(q.z >> 16));
        x[6] = b2f((u16)q.w); x[7] = b2f((u16)(q.w >> 16));
        if (base + 8 <= NK) {
            #pragma unroll
            for (int j = 0; j < 8; j++) { double d = (double)x[j]; S += d; Q += d * d; }
        } else {
            #pragma unroll
            for (int j = 0; j < 8; j++) {
                if (base + j < NK) { double d = (double)x[j]; S += d; Q += d * d; }
            }
        }
    }
    sS[t] = S; sQ[t] = Q;
    __syncthreads();
    for (int o = 128; o > 0; o >>= 1) {
        if (t < o) { sS[t] += sS[t + o]; sQ[t] += sQ[t + o]; }
        __syncthreads();
    }
    if (t == 0) {
        part2c[(size_t)blockIdx.x * 2] = sS[0];
        part2c[(size_t)blockIdx.x * 2 + 1] = sQ[0];
    }
}

// 256-point tile x 32-channel group per block. Staging tile packed to bf16
// pairs (u32) -> LDS 43.5 KB -> ~27 KB -> 5 blocks/CU (was 3). h2 in
// registers; channel pairs computed together (2 accumulators, ~80 VGPR, no
// spills). Cooperative u32 writes: 4 rows x 64 B per instruction. Fused fin2.
__global__ __launch_bounds__(256) void k_passOut(const void* __restrict__ W3, const void* __restrict__ b3,
                                                 const void* __restrict__ g2, const void* __restrict__ be2,
                                                 const u32* dflag, const u32* nkept,
                                                 const double* __restrict__ part2c,
                                                 const float* __restrict__ z2z,
                                                 const u16* __restrict__ z2b,
                                                 u16* __restrict__ out3b) {
    __shared__ __align__(16) float w3L[32][68]; // w3L[cl][j] = W3[j][c0+cl]
    __shared__ __align__(16) float aK2[64], aC2[64], aB3g[32];
    __shared__ u32 st32[256][17];               // [pt][ch-pair], 17.4 KB, 2-way aliasing free
    int t = threadIdx.x;
    int pb = blockIdx.x >> 2, cg = blockIdx.x & 3;
    int c0 = cg * 32;
    int NK = min((int)*nkept, PCAP);
    int rowbase = pb * 256;
    if (rowbase >= NK) return;               // uniform early-out
    bool bf = *dflag != 0;
    for (int idx = t; idx < 2048; idx += 256) {
        int j = idx & 63, cl = idx >> 6;
        w3L[cl][j] = ld1(W3, j * 128 + c0 + cl, bf);
    }
    if (t < 64) {                             // fused fin2
        double S = 0.0, Q = 0.0;
        #pragma unroll
        for (int seg = 0; seg < SZSEG; seg++) {
            S += part2c[(size_t)(seg * 64 + t) * 2];
            Q += part2c[(size_t)(seg * 64 + t) * 2 + 1];
        }
        double Zn = (double)(NTOT - NK);
        double zz = (double)z2z[t];
        double mu = (S + Zn * zz) / (double)NTOT;
        double var = (Q + Zn * zz * zz) / (double)NTOT - mu * mu;
        if (var < 0.0) var = 0.0;
        float rs = (float)(1.0 / sqrt(var + 1e-5));
        float k2 = rs * ld1(g2, t, bf);
        aK2[t] = k2;
        aC2[t] = ld1(be2, t, bf) - (float)mu * k2;
    }
    if (t < 32) aB3g[t] = ld1(b3, c0 + t, bf);
    __syncthreads();
    int i = rowbase + t;
    if (i < NK) {
        float4 h2v[16];
        #pragma unroll
        for (int qq = 0; qq < 16; qq++) {
            float4 kk = *(const float4*)&aK2[4 * qq];
            float4 cc = *(const float4*)&aC2[4 * qq];
            float4 z;
            z.x = b2f(z2b[(size_t)(4 * qq + 0) * PCAP + i]);
            z.y = b2f(z2b[(size_t)(4 * qq + 1) * PCAP + i]);
            z.z = b2f(z2b[(size_t)(4 * qq + 2) * PCAP + i]);
            z.w = b2f(z2b[(size_t)(4 * qq + 3) * PCAP + i]);
            h2v[qq] = make_float4(fmaxf(z.x * kk.x + cc.x, 0.f), fmaxf(z.y * kk.y + cc.y, 0.f),
                                  fmaxf(z.z * kk.z + cc.z, 0.f), fmaxf(z.w * kk.w + cc.w, 0.f));
        }
        #pragma unroll 2
        for (int cl = 0; cl < 32; cl += 2) {
            float a0 = aB3g[cl], a1 = aB3g[cl + 1];
            #pragma unroll
            for (int qq = 0; qq < 16; qq++) {
                float4 w0 = *(const float4*)&w3L[cl][4 * qq];
                float4 w1 = *(const float4*)&w3L[cl + 1][4 * qq];
                a0 += h2v[qq].x * w0.x + h2v[qq].y * w0.y + h2v[qq].z * w0.z + h2v[qq].w * w0.w;
                a1 += h2v[qq].x * w1.x + h2v[qq].y * w1.y + h2v[qq].z * w1.z + h2v[qq].w * w1.w;
            }
            st32[t][cl >> 1] = (u32)f2b(a0) | ((u32)f2b(a1) << 16);
        }
    }
    __syncthreads();
    // cooperative u32 writes: lane = ch-pair (16 per row), 4 rows x 64 B per instr
    u32* out32 = (u32*)out3b;
    int lc2 = t & 15, r0 = t >> 4;
    #pragma unroll 4
    for (int k = 0; k < 16; k++) {
        int r = r0 + k * 16;
        int gi = rowbase + r;
        if (gi < NK) out32[(size_t)gi * 64 + (c0 >> 1) + lc2] = st32[r][lc2];
    }
}

// per-(voxel,channel-pair) max: u32 loads/stores halve instruction count and
// give 4B-coalesced access; bf16 max on packed halves is exact.
__global__ void k_maxOut(const u16* __restrict__ out3b, const u32* __restrict__ slotctr,
                         const u32* __restrict__ voxbase, const u32* dflag, void* __restrict__ out) {
    int tid = blockIdx.x * 256 + threadIdx.x;
    int c2 = tid & 63;           // channel pair index (2*c2, 2*c2+1)
    int v = tid >> 6;
    if (v >= MAXV) return;
    bool bf = *dflag != 0;
    int len = min((int)slotctr[v], MAXP);
    u32 base = voxbase[v];
    const u32* col = (const u32*)out3b;
    float m0 = __uint_as_float(0xFF800000u), m1 = m0; // -inf
    for (int s = 0; s < len; s++) {
        u32 p = base + s;
        if (p < PCAP) {
            u32 q = col[(size_t)p * 64 + c2];
            m0 = fmaxf(m0, __uint_as_float(q << 16));
            m1 = fmaxf(m1, __uint_as_float(q & 0xFFFF0000u));
        }
    }
    if (bf) {
        ((u32*)out)[(size_t)v * 64 + c2] = ((u32)f2b(m0)) | ((u32)f2b(m1) << 16);
    } else {
        float* of = (float*)out;
        of[(size_t)v * 128 + 2 * c2] = m0;
        of[(size_t)v * 128 + 2 * c2 + 1] = m1;
    }
}

// ---------- launch ----------
extern "C" void kernel_launch(void* const* d_in, const int* in_sizes, int n_in,
                              void* d_out, int out_size, void* d_ws, size_t ws_size,
                              hipStream_t stream) {
    const void* pts = d_in[0];
    const void* W1 = d_in[1];
    const void* b1 = d_in[2];
    const void* g1 = d_in[3];
    const void* be1 = d_in[4];
    const void* W2 = d_in[5];
    const void* b2 = d_in[6];
    const void* g2 = d_in[7];
    const void* be2 = d_in[8];
    const void* W3 = d_in[9];
    const void* b3 = d_in[10];

    char* ws = (char*)d_ws;
    size_t off = 0;
    auto alloc = [&](size_t bytes) -> size_t {
        size_t o = off;
        off = (off + bytes + 255) & ~(size_t)255;
        return o;
    };
    size_t zstart = off;
    u32* occ = (u32*)(ws + alloc((size_t)NW * 4));
    u32* slotctr = (u32*)(ws + alloc((size_t)MAXV * 4));
    size_t zend = off;
    u32* wordbase = (u32*)(ws + alloc((size_t)NW * 4));  // memset 0xFF
    u32* voxbase = (u32*)(ws + alloc((size_t)MAXV * 4));
    u32* bsums = (u32*)(ws + alloc((size_t)SNB * 4));
    u32* vbsums = (u32*)(ws + alloc((size_t)VB * 4));
    int* firstkey = (int*)(ws + alloc(256));
    u32* dflag = (u32*)(ws + alloc(256));
    u32* nkept = (u32*)(ws + alloc(256));
    float* mu1 = (float*)(ws + alloc(256));
    float* rs1 = (float*)(ws + alloc(256));
    float* z2z = (float*)(ws + alloc(256));
    double* part1 = (double*)(ws + alloc((size_t)S1B * 128 * 8));
    double* part2c = (double*)(ws + alloc((size_t)64 * SZSEG * 2 * 8));
    float4* slotted = (float4*)(ws + alloc((size_t)NTOT * 16));
    float4* cpt = (float4*)(ws + alloc((size_t)PCAP * 16));
    u16* z2b = (u16*)(ws + alloc((size_t)64 * PCAP * 2));
    u16* out3b = (u16*)(ws + alloc((size_t)PCAP * 128 * 2));
    if (off > ws_size) return; // workspace too small

    hipMemsetAsync(ws + zstart, 0, zend - zstart, stream);
    hipMemsetAsync(wordbase, 0xFF, (size_t)NW * 4, stream);

    k_detect<<<1, 256, 0, stream>>>(pts, dflag, firstkey);
    k_hist<<<(NPTS + 255) / 256, 256, 0, stream>>>(pts, dflag, occ);
    k_scan1<<<SNB, 256, 0, stream>>>(occ, bsums, firstkey);
    k_scan3<<<SNB, 256, 0, stream>>>(occ, bsums, firstkey, dflag, wordbase, d_out);
    k_gather<<<(NPTS + 255) / 256, 256, 0, stream>>>(pts, occ, wordbase, dflag, slotctr, slotted);
    k_vox1<<<VB, 256, 0, stream>>>(slotctr, vbsums);
    k_vox3<<<VB, 256, 0, stream>>>(slotctr, vbsums, voxbase, slotted, cpt, nkept);
    k_stats1<<<S1B, 256, 0, stream>>>(W1, b1, dflag, nkept, cpt, part1);
    k_fin1<<<1, 256, 0, stream>>>(b1, g1, be1, W2, b2, dflag, nkept, part1, mu1, rs1, z2z);
    k_passZ2<<<(PCAP / 512) * 2, 256, 0, stream>>>(W1, b1, g1, be1, W2, b2, dflag, nkept, mu1, rs1, cpt, z2b);
    k_statsZ<<<64 * SZSEG, 256, 0, stream>>>(z2b, nkept, part2c);
    k_passOut<<<(PCAP / 256) * 4, 256, 0, stream>>>(W3, b3, g2, be2, dflag, nkept, part2c, z2z, z2b, out3b);
    k_maxOut<<<(64 * MAXV) / 256, 256, 0, stream>>>(out3b, slotctr, voxbase, dflag, d_out);
}

// Round 16
// 307.021 us; speedup vs baseline: 1.0341x; 1.0341x over previous
//
#include <hip/hip_runtime.h>
#include <stdint.h>

typedef unsigned int u32;
typedef unsigned short u16;

#define NPTS 1000000
#define DIMD 500
#define DIMH 500
#define DIMW 40
#define NVOX 10000000      // DIMD*DIMH*DIMW
#define NW 312500          // NVOX/32 occupancy-bitmask words
#define MAXV 40000
#define MAXP 32
#define NTOT (MAXV * MAXP) // 1,280,000 rows in the flat MLP input
#define PCAP 65536         // compact kept-point capacity (expected ~42k)
#define OUTV (MAXV * 128)  // 5,120,000 voxel_out elements
#define WCHUNK 4096        // bitmask words per scan block
#define SNB ((NW + WCHUNK - 1) / WCHUNK) // 77 scan blocks
#define S1B 256            // stats1 grid
#define VB ((MAXV + 255) / 256)          // 157 vox-scan blocks
#define SZSEG 4            // statsZ row-segments per channel

// ---------- helpers ----------
__device__ __forceinline__ float b2f(u16 h) { return __uint_as_float(((u32)h) << 16); }

__device__ __forceinline__ u16 f2b(float f) {
    u32 u = __float_as_uint(f);
    if ((u & 0x7F800000u) == 0x7F800000u) {           // inf / nan
        u16 h = (u16)(u >> 16);
        if (u & 0x007FFFFFu) h |= 0x40;               // quiet nan
        return h;
    }
    u32 lsb = (u >> 16) & 1u;
    return (u16)((u + 0x7FFFu + lsb) >> 16);          // round-to-nearest-even
}

// dtype-adaptive element load/store. bf==true -> bf16 (u16), else f32.
__device__ __forceinline__ float ld1(const void* p, int i, bool bf) {
    return bf ? b2f(((const u16*)p)[i]) : ((const float*)p)[i];
}
__device__ __forceinline__ float4 ld4(const void* p, int i4, bool bf) {
    if (bf) {
        ushort4 q = ((const ushort4*)p)[i4];
        return make_float4(b2f(q.x), b2f(q.y), b2f(q.z), b2f(q.w));
    }
    return ((const float4*)p)[i4];
}
__device__ __forceinline__ void st1(void* p, size_t i, float v, bool bf) {
    if (bf) ((u16*)p)[i] = f2b(v);
    else ((float*)p)[i] = v;
}

// exact replica of ((xyz - RANGE_MIN)/VOXEL_SIZE).astype(int32) + validity (f32 ops)
__device__ __forceinline__ bool pkey(float x, float y, float z, int& key) {
    float fx = (x - (-50.0f)) / 0.2f;
    float fy = (y - (-50.0f)) / 0.2f;
    float fz = (z - (-3.0f)) / 0.2f;
    int ix = (int)fx, iy = (int)fy, iz = (int)fz;
    if (ix < 0 || ix >= DIMD || iy < 0 || iy >= DIMH || iz < 0 || iz >= DIMW) return false;
    key = ix * (DIMH * DIMW) + iy * DIMW + iz;
    return true;
}

// ---------- kernels ----------

// Detect input dtype (bf16 vs f32) from points' bit patterns. Also inits firstkey.
__global__ void k_detect(const void* pts, u32* dflag, int* firstkey) {
    __shared__ int s[256];
    int t = threadIdx.x;
    const u16* p = (const u16*)pts;
    int good = 0;
    for (int i = 0; i < 16; i++) {
        u16 v = p[(size_t)(t * 16 + i) * 2];
        int e = (v >> 7) & 0xFF;
        if (e >= 90 && e <= 140) good++;
    }
    s[t] = good;
    __syncthreads();
    for (int o = 128; o > 0; o >>= 1) {
        if (t < o) s[t] += s[t + o];
        __syncthreads();
    }
    if (t == 0) {
        *dflag = (s[0] >= (4096 * 3) / 5) ? 1u : 0u;
        *firstkey = 0x7FFFFFFF;
    }
}

// occupancy bitmask
__global__ void k_hist(const void* __restrict__ pts, const u32* dflag, u32* __restrict__ occ) {
    int i = blockIdx.x * 256 + threadIdx.x;
    if (i >= NPTS) return;
    bool bf = *dflag != 0;
    float4 p = ld4(pts, i, bf);
    int key;
    if (pkey(p.x, p.y, p.z, key)) atomicOr(&occ[key >> 5], 1u << (key & 31));
}

__global__ void k_scan1(const u32* __restrict__ occ, u32* bsums, int* firstkey) {
    __shared__ int s[256];
    __shared__ int sm[256];
    int t = threadIdx.x;
    int base = blockIdx.x * WCHUNK + t * 16;
    int tot = 0, mn = 0x7FFFFFFF;
    for (int i = 0; i < 16; i++) {
        int w = base + i;
        if (w < NW) {
            u32 x = occ[w];
            tot += __popc(x);
            if (x && mn == 0x7FFFFFFF) mn = w * 32 + __builtin_ctz(x);
        }
    }
    s[t] = tot; sm[t] = mn;
    __syncthreads();
    for (int o = 128; o > 0; o >>= 1) {
        if (t < o) { s[t] += s[t + o]; sm[t] = min(sm[t], sm[t + o]); }
        __syncthreads();
    }
    if (t == 0) {
        bsums[blockIdx.x] = (u32)s[0];
        if (sm[0] != 0x7FFFFFFF) atomicMin(firstkey, sm[0]);
    }
}

// per-word rank bases (only where rank can be < MAXV) + coords + fused pad.
__global__ void k_scan3(const u32* __restrict__ occ, const u32* __restrict__ bsums,
                        const int* __restrict__ firstkey, const u32* dflag,
                        u32* __restrict__ wordbase, void* __restrict__ out) {
    __shared__ int s[256];
    __shared__ u32 red[256];
    __shared__ u32 sboff, stot;
    int t = threadIdx.x;
    bool bf = *dflag != 0;
    red[t] = (t < (int)SNB && t < (int)blockIdx.x) ? bsums[t] : 0u;
    __syncthreads();
    for (int o = 128; o > 0; o >>= 1) {
        if (t < o) red[t] += red[t + o];
        __syncthreads();
    }
    if (t == 0) sboff = red[0];
    __syncthreads();
    if (blockIdx.x == 0) {                      // total occupied (for pad path)
        red[t] = (t < (int)SNB) ? bsums[t] : 0u;
        __syncthreads();
        for (int o = 128; o > 0; o >>= 1) {
            if (t < o) red[t] += red[t + o];
            __syncthreads();
        }
        if (t == 0) stot = red[0];
        __syncthreads();
    }
    u32 boff = sboff;
    if (blockIdx.x != 0 && boff >= (u32)MAXV) return;  // nothing to write here
    int base = blockIdx.x * WCHUNK + t * 16;
    int tot = 0;
    for (int i = 0; i < 16; i++) {
        int w = base + i;
        if (w < NW) tot += __popc(occ[w]);
    }
    s[t] = tot;
    __syncthreads();
    for (int o = 1; o < 256; o <<= 1) {
        int v = (t >= o) ? s[t - o] : 0;
        __syncthreads();
        s[t] += v;
        __syncthreads();
    }
    int run = (int)boff + s[t] - tot;
    for (int i = 0; i < 16; i++) {
        if (run >= MAXV) break;
        int w = base + i;
        if (w >= NW) break;
        u32 x = occ[w];
        wordbase[w] = (u32)run;
        u32 xx = x;
        int r = run;
        while (xx) {
            int b = __builtin_ctz(xx);
            xx &= xx - 1;
            if (r < MAXV) {
                int key = w * 32 + b;
                int ix = key / 20000;
                int rem = key - ix * 20000;
                int iy = rem / 40;
                int iz = rem - iy * 40;
                size_t o4 = (size_t)OUTV + (size_t)r * 4;
                st1(out, o4 + 0, 0.0f, bf);
                st1(out, o4 + 1, (float)ix, bf);
                st1(out, o4 + 2, (float)iy, bf);
                st1(out, o4 + 3, (float)iz, bf);
            }
            r++;
        }
        run += __popc(x);
    }
    // fused pad (only if fewer than MAXV occupied voxels — rare edge case)
    if (blockIdx.x == 0) {
        int to = (int)stot;
        int fk = *firstkey;
        if (fk >= NVOX || fk < 0) fk = 0;
        int ix = fk / 20000, rem = fk - ix * 20000, iy = rem / 40, iz = rem - iy * 40;
        for (int r = to + t; r < MAXV; r += 256) {
            size_t o4 = (size_t)OUTV + (size_t)r * 4;
            st1(out, o4 + 0, 0.0f, bf);
            st1(out, o4 + 1, (float)ix, bf);
            st1(out, o4 + 2, (float)iy, bf);
            st1(out, o4 + 3, (float)iz, bf);
        }
    }
}

// single 1M-point pass with early-exit on wordbase (0xFFFFFFFF where rank >= MAXV)
__global__ void k_gather(const void* __restrict__ pts, const u32* __restrict__ occ,
                         const u32* __restrict__ wordbase, const u32* dflag,
                         u32* __restrict__ slotctr, float4* __restrict__ slotted) {
    int i = blockIdx.x * 256 + threadIdx.x;
    if (i >= NPTS) return;
    bool bf = *dflag != 0;
    float4 p = ld4(pts, i, bf);
    int key;
    if (!pkey(p.x, p.y, p.z, key)) return;
    int w = key >> 5, b = key & 31;
    u32 wb = wordbase[w];
    if (wb >= (u32)MAXV) return;               // fast path out
    int rank = (int)wb + __popc(occ[w] & ((1u << b) - 1u));
    if (rank >= MAXV) return;
    u32 slot = atomicAdd(&slotctr[rank], 1u);
    if (slot >= MAXP) return;
    slotted[(size_t)rank * MAXP + slot] = p;
}

// per-block sums of min(slotctr,32)
__global__ void k_vox1(const u32* __restrict__ slotctr, u32* __restrict__ vbsums) {
    __shared__ u32 s[256];
    int t = threadIdx.x;
    int v = blockIdx.x * 256 + t;
    u32 cnt = (v < MAXV) ? min(slotctr[v], (u32)MAXP) : 0u;
    s[t] = cnt;
    __syncthreads();
    for (int o = 128; o > 0; o >>= 1) {
        if (t < o) s[t] += s[t + o];
        __syncthreads();
    }
    if (t == 0) vbsums[blockIdx.x] = s[0];
}

// intra-block scan -> voxbase + compaction; inline vboffs reduction; block 0 writes nkept.
__global__ void k_vox3(const u32* __restrict__ slotctr, const u32* __restrict__ vbsums,
                       u32* __restrict__ voxbase, const float4* __restrict__ slotted,
                       float4* __restrict__ cpt, u32* __restrict__ nkept) {
    __shared__ u32 s[256];
    __shared__ u32 red[256];
    __shared__ u32 sboff;
    int t = threadIdx.x;
    int v = blockIdx.x * 256 + t;
    red[t] = (t < VB && t < (int)blockIdx.x) ? vbsums[t] : 0u;
    __syncthreads();
    for (int o = 128; o > 0; o >>= 1) {
        if (t < o) red[t] += red[t + o];
        __syncthreads();
    }
    if (t == 0) sboff = red[0];
    __syncthreads();
    if (blockIdx.x == 0) {
        red[t] = (t < VB) ? vbsums[t] : 0u;
        __syncthreads();
        for (int o = 128; o > 0; o >>= 1) {
            if (t < o) red[t] += red[t + o];
            __syncthreads();
        }
        if (t == 0) *nkept = red[0];
        __syncthreads();
    }
    u32 cnt = (v < MAXV) ? min(slotctr[v], (u32)MAXP) : 0u;
    s[t] = cnt;
    __syncthreads();
    for (int o = 1; o < 256; o <<= 1) {
        u32 x = (t >= o) ? s[t - o] : 0u;
        __syncthreads();
        s[t] += x;
        __syncthreads();
    }
    if (v < MAXV) {
        u32 base = sboff + s[t] - cnt;
        voxbase[v] = base;
        for (int sl = 0; sl < (int)cnt; sl++) {
            u32 p = base + sl;
            if (p < PCAP) cpt[p] = slotted[(size_t)v * MAXP + sl];
        }
    }
}

// layer-1 pre-BN stats: wave-walk over compact list, lane=channel, f64 reg accum
__global__ __launch_bounds__(256) void k_stats1(const void* __restrict__ W1, const void* __restrict__ b1,
                                                const u32* dflag, const u32* nkept,
                                                const float4* __restrict__ cpt,
                                                double* __restrict__ part1) {
    __shared__ double ls[4][64], lq[4][64];
    int t = threadIdx.x, lane = t & 63, w = t >> 6;
    bool bf = *dflag != 0;
    float w0 = ld1(W1, 0 * 64 + lane, bf);
    float w1 = ld1(W1, 1 * 64 + lane, bf);
    float w2 = ld1(W1, 2 * 64 + lane, bf);
    float w3 = ld1(W1, 3 * 64 + lane, bf);
    float bb = ld1(b1, lane, bf);
    int P = min((int)*nkept, PCAP);
    int G = gridDim.x * 4, gw = blockIdx.x * 4 + w;
    double S = 0.0, Q = 0.0;
    for (int p = gw; p < P; p += G) {
        float4 f = cpt[p];                  // wave-uniform -> broadcast
        float z = f.x * w0 + f.y * w1 + f.z * w2 + f.w * w3 + bb;
        S += (double)z;
        Q += (double)z * (double)z;
    }
    ls[w][lane] = S; lq[w][lane] = Q;
    __syncthreads();
    if (t < 64) {
        double SS = ls[0][t] + ls[1][t] + ls[2][t] + ls[3][t];
        double QQ = lq[0][t] + lq[1][t] + lq[2][t] + lq[3][t];
        part1[(size_t)blockIdx.x * 128 + t] = SS;
        part1[(size_t)blockIdx.x * 128 + 64 + t] = QQ;
    }
}

__global__ void k_fin1(const void* __restrict__ b1, const void* __restrict__ g1, const void* __restrict__ be1,
                       const void* __restrict__ W2, const void* __restrict__ b2,
                       const u32* dflag, const u32* nkept, const double* __restrict__ part1,
                       float* mu1, float* rs1, float* z2z) {
    __shared__ double accS[4][64], accQ[4][64];
    __shared__ float h1s[64];
    int t = threadIdx.x, q = t >> 6, c = t & 63; // 256 threads
    bool bf = *dflag != 0;
    double S = 0.0, Q = 0.0;
    for (int b = q; b < S1B; b += 4) {
        S += part1[(size_t)b * 128 + c];
        Q += part1[(size_t)b * 128 + 64 + c];
    }
    accS[q][c] = S; accQ[q][c] = Q;
    __syncthreads();
    if (t < 64) {
        S = accS[0][t] + accS[1][t] + accS[2][t] + accS[3][t];
        Q = accQ[0][t] + accQ[1][t] + accQ[2][t] + accQ[3][t];
        int P = min((int)*nkept, PCAP);
        double Zn = (double)(NTOT - P);
        double bb = (double)ld1(b1, t, bf);
        double mu = (S + Zn * bb) / (double)NTOT;
        double var = (Q + Zn * bb * bb) / (double)NTOT - mu * mu;
        if (var < 0.0) var = 0.0;
        float rs = (float)(1.0 / sqrt(var + 1e-5));
        float muf = (float)mu;
        mu1[t] = muf;
        rs1[t] = rs;
        float h = ((float)bb - muf) * rs * ld1(g1, t, bf) + ld1(be1, t, bf);
        h1s[t] = h > 0.f ? h : 0.f;
    }
    __syncthreads();
    if (t < 64) {
        float acc = ld1(b2, t, bf);
        for (int j = 0; j < 64; j++) acc += h1s[j] * ld1(W2, j * 64 + t, bf);
        z2z[t] = acc;
    }
}

// 2 points/thread, 32-channel group per block: h1 in regs, broadcast weight reads.
// z2buf column-major bf16 (coalesced, half traffic).
__global__ __launch_bounds__(256, 2) void k_passZ2(const void* __restrict__ W1, const void* __restrict__ b1,
                                                   const void* __restrict__ g1, const void* __restrict__ be1,
                                                   const void* __restrict__ W2, const void* __restrict__ b2,
                                                   const u32* dflag, const u32* nkept,
                                                   const float* __restrict__ mu1, const float* __restrict__ rs1,
                                                   const float4* __restrict__ cpt,
                                                   u16* __restrict__ z2b) {
    __shared__ __align__(16) float w2L[32][68];  // w2L[cl][j] = W2[j][c0+cl]
    __shared__ __align__(16) float sW1[4][64];
    __shared__ __align__(16) float aB1[64], aK1[64], aC1[64], aB2g[32];
    int t = threadIdx.x;
    int pb = blockIdx.x >> 1, cg = blockIdx.x & 1;
    int c0 = cg * 32;
    bool bf = *dflag != 0;
    for (int idx = t; idx < 2048; idx += 256) {
        int j = idx & 63, cl = idx >> 6;         // j-fastest -> conflict-free LDS writes
        w2L[cl][j] = ld1(W2, j * 64 + c0 + cl, bf);
    }
    if (t < 64) {
        sW1[0][t] = ld1(W1, t, bf);
        sW1[1][t] = ld1(W1, 64 + t, bf);
        sW1[2][t] = ld1(W1, 128 + t, bf);
        sW1[3][t] = ld1(W1, 192 + t, bf);
        aB1[t] = ld1(b1, t, bf);
        float k1 = rs1[t] * ld1(g1, t, bf);
        aK1[t] = k1;
        aC1[t] = ld1(be1, t, bf) - mu1[t] * k1;
    }
    if (t < 32) aB2g[t] = ld1(b2, c0 + t, bf);
    __syncthreads();
    int NK = min((int)*nkept, PCAP);
    int i = pb * 512 + t;
    int i2 = i + 256;
    if (i >= NK) return;
    bool has2 = i2 < NK;
    float4 f0 = cpt[i];
    float4 f1 = cpt[has2 ? i2 : i];
    float4 h0[16], h1[16];
    #pragma unroll
    for (int qq = 0; qq < 16; qq++) {
        float4 a = *(const float4*)&sW1[0][4 * qq];
        float4 b = *(const float4*)&sW1[1][4 * qq];
        float4 cc = *(const float4*)&sW1[2][4 * qq];
        float4 d = *(const float4*)&sW1[3][4 * qq];
        float4 bb = *(const float4*)&aB1[4 * qq];
        float4 kk = *(const float4*)&aK1[4 * qq];
        float4 c1 = *(const float4*)&aC1[4 * qq];
        float4 z;
        z.x = f0.x * a.x + f0.y * b.x + f0.z * cc.x + f0.w * d.x + bb.x;
        z.y = f0.x * a.y + f0.y * b.y + f0.z * cc.y + f0.w * d.y + bb.y;
        z.z = f0.x * a.z + f0.y * b.z + f0.z * cc.z + f0.w * d.z + bb.z;
        z.w = f0.x * a.w + f0.y * b.w + f0.z * cc.w + f0.w * d.w + bb.w;
        h0[qq] = make_float4(fmaxf(z.x * kk.x + c1.x, 0.f), fmaxf(z.y * kk.y + c1.y, 0.f),
                             fmaxf(z.z * kk.z + c1.z, 0.f), fmaxf(z.w * kk.w + c1.w, 0.f));
        z.x = f1.x * a.x + f1.y * b.x + f1.z * cc.x + f1.w * d.x + bb.x;
        z.y = f1.x * a.y + f1.y * b.y + f1.z * cc.y + f1.w * d.y + bb.y;
        z.z = f1.x * a.z + f1.y * b.z + f1.z * cc.z + f1.w * d.z + bb.z;
        z.w = f1.x * a.w + f1.y * b.w + f1.z * cc.w + f1.w * d.w + bb.w;
        h1[qq] = make_float4(fmaxf(z.x * kk.x + c1.x, 0.f), fmaxf(z.y * kk.y + c1.y, 0.f),
                             fmaxf(z.z * kk.z + c1.z, 0.f), fmaxf(z.w * kk.w + c1.w, 0.f));
    }
    for (int cl = 0; cl < 32; cl++) {
        float a0 = aB2g[cl], a1 = a0;
        #pragma unroll
        for (int qq = 0; qq < 16; qq++) {
            float4 wv = *(const float4*)&w2L[cl][4 * qq];
            a0 += h0[qq].x * wv.x + h0[qq].y * wv.y + h0[qq].z * wv.z + h0[qq].w * wv.w;
            a1 += h1[qq].x * wv.x + h1[qq].y * wv.y + h1[qq].z * wv.z + h1[qq].w * wv.w;
        }
        size_t cb = (size_t)(c0 + cl) * PCAP;
        z2b[cb + i] = f2b(a0);                 // lanes consecutive -> coalesced
        if (has2) z2b[cb + i2] = f2b(a1);
    }
}

// per-(channel,segment) column sum/sumsq of z2b: 256 blocks, 16B vector loads
__global__ __launch_bounds__(256) void k_statsZ(const u16* __restrict__ z2b, const u32* nkept,
                                                double* __restrict__ part2c) {
    __shared__ double sS[256], sQ[256];
    int c = blockIdx.x & 63, seg = blockIdx.x >> 6;
    int t = threadIdx.x;
    int NK = min((int)*nkept, PCAP);
    int nvec = (NK + 7) >> 3;                 // # of 8-elem (16B) vectors
    int per = (nvec + SZSEG - 1) / SZSEG;
    int lo = seg * per, hi = min(lo + per, nvec);
    const uint4* col = (const uint4*)(z2b + (size_t)c * PCAP); // 16B-aligned
    double S = 0.0, Q = 0.0;
    for (int iv = lo + t; iv < hi; iv += 256) {
        uint4 q = col[iv];
        int base = iv * 8;
        float x[8];
        x[0] = b2f((u16)q.x); x[1] = b2f((u16)(q.x >> 16));
        x[2] = b2f((u16)q.y); x[3] = b2f((u16)(q.y >> 16));
        x[4] = b2f((u16)q.z); x[5] = b2f((u16)(q.z >> 16));
        x[6] = b2f((u16)q.w); x[7] = b2f((u16)(q.w >> 16));
        if (base + 8 <= NK) {
            #pragma unroll
            for (int j = 0; j < 8; j++) { double d = (double)x[j]; S += d; Q += d * d; }
        } else {
            #pragma unroll
            for (int j = 0; j < 8; j++) {
                if (base + j < NK) { double d = (double)x[j]; S += d; Q += d * d; }
            }
        }
    }
    sS[t] = S; sQ[t] = Q;
    __syncthreads();
    for (int o = 128; o > 0; o >>= 1) {
        if (t < o) { sS[t] += sS[t + o]; sQ[t] += sQ[t + o]; }
        __syncthreads();
    }
    if (t == 0) {
        part2c[(size_t)blockIdx.x * 2] = sS[0];
        part2c[(size_t)blockIdx.x * 2 + 1] = sQ[0];
    }
}

// 256-point tile x 32-channel group per block (round-14 best: VGPR 80, zero
// bank conflicts, 46 us). Fused fin2; h2 in registers; LDS-staged full-line
// bf16 stores.
__global__ __launch_bounds__(256) void k_passOut(const void* __restrict__ W3, const void* __restrict__ b3,
                                                 const void* __restrict__ g2, const void* __restrict__ be2,
                                                 const u32* dflag, const u32* nkept,
                                                 const double* __restrict__ part2c,
                                                 const float* __restrict__ z2z,
                                                 const u16* __restrict__ z2b,
                                                 u16* __restrict__ out3b) {
    __shared__ __align__(16) float w3L[32][68]; // w3L[cl][j] = W3[j][c0+cl]
    __shared__ __align__(16) float aK2[64], aC2[64], aB3g[32];
    __shared__ __align__(16) float st[256][33]; // [pt][ch], stride 33 -> conflict-free
    int t = threadIdx.x;
    int pb = blockIdx.x >> 2, cg = blockIdx.x & 3;
    int c0 = cg * 32;
    int NK = min((int)*nkept, PCAP);
    int rowbase = pb * 256;
    if (rowbase >= NK) return;               // uniform early-out
    bool bf = *dflag != 0;
    for (int idx = t; idx < 2048; idx += 256) {
        int j = idx & 63, cl = idx >> 6;
        w3L[cl][j] = ld1(W3, j * 128 + c0 + cl, bf);
    }
    if (t < 64) {                             // fused fin2
        double S = 0.0, Q = 0.0;
        #pragma unroll
        for (int seg = 0; seg < SZSEG; seg++) {
            S += part2c[(size_t)(seg * 64 + t) * 2];
            Q += part2c[(size_t)(seg * 64 + t) * 2 + 1];
        }
        double Zn = (double)(NTOT - NK);
        double zz = (double)z2z[t];
        double mu = (S + Zn * zz) / (double)NTOT;
        double var = (Q + Zn * zz * zz) / (double)NTOT - mu * mu;
        if (var < 0.0) var = 0.0;
        float rs = (float)(1.0 / sqrt(var + 1e-5));
        float k2 = rs * ld1(g2, t, bf);
        aK2[t] = k2;
        aC2[t] = ld1(be2, t, bf) - (float)mu * k2;
    }
    if (t < 32) aB3g[t] = ld1(b3, c0 + t, bf);
    __syncthreads();
    int i = rowbase + t;
    if (i < NK) {
        float4 h2v[16];
        #pragma unroll
        for (int qq = 0; qq < 16; qq++) {
            float4 kk = *(const float4*)&aK2[4 * qq];
            float4 cc = *(const float4*)&aC2[4 * qq];
            float4 z;
            z.x = b2f(z2b[(size_t)(4 * qq + 0) * PCAP + i]);
            z.y = b2f(z2b[(size_t)(4 * qq + 1) * PCAP + i]);
            z.z = b2f(z2b[(size_t)(4 * qq + 2) * PCAP + i]);
            z.w = b2f(z2b[(size_t)(4 * qq + 3) * PCAP + i]);
            h2v[qq] = make_float4(fmaxf(z.x * kk.x + cc.x, 0.f), fmaxf(z.y * kk.y + cc.y, 0.f),
                                  fmaxf(z.z * kk.z + cc.z, 0.f), fmaxf(z.w * kk.w + cc.w, 0.f));
        }
        #pragma unroll 4
        for (int cl = 0; cl < 32; cl++) {
            float a0 = aB3g[cl];
            #pragma unroll
            for (int qq = 0; qq < 16; qq++) {
                float4 wv = *(const float4*)&w3L[cl][4 * qq];
                a0 += h2v[qq].x * wv.x + h2v[qq].y * wv.y + h2v[qq].z * wv.z + h2v[qq].w * wv.w;
            }
            st[t][cl] = a0;                  // direct write: h2v stays in regs
        }
    }
    __syncthreads();
    // cooperative full-line writes: lanes = 32 consecutive channels x 8 rows
    int lc = t & 31, r0 = t >> 5;
    #pragma unroll 4
    for (int k = 0; k < 32; k++) {
        int r = r0 + k * 8;
        int gi = rowbase + r;
        if (gi < NK) out3b[(size_t)gi * 128 + c0 + lc] = f2b(st[r][lc]);
    }
}

// per-(voxel,channel-pair) max: u32 loads/stores halve instruction count and
// give 4B-coalesced access; bf16 max on packed halves is exact.
__global__ void k_maxOut(const u16* __restrict__ out3b, const u32* __restrict__ slotctr,
                         const u32* __restrict__ voxbase, const u32* dflag, void* __restrict__ out) {
    int tid = blockIdx.x * 256 + threadIdx.x;
    int c2 = tid & 63;           // channel pair index (2*c2, 2*c2+1)
    int v = tid >> 6;
    if (v >= MAXV) return;
    bool bf = *dflag != 0;
    int len = min((int)slotctr[v], MAXP);
    u32 base = voxbase[v];
    const u32* col = (const u32*)out3b;
    float m0 = __uint_as_float(0xFF800000u), m1 = m0; // -inf
    for (int s = 0; s < len; s++) {
        u32 p = base + s;
        if (p < PCAP) {
            u32 q = col[(size_t)p * 64 + c2];
            m0 = fmaxf(m0, __uint_as_float(q << 16));
            m1 = fmaxf(m1, __uint_as_float(q & 0xFFFF0000u));
        }
    }
    if (bf) {
        ((u32*)out)[(size_t)v * 64 + c2] = ((u32)f2b(m0)) | ((u32)f2b(m1) << 16);
    } else {
        float* of = (float*)out;
        of[(size_t)v * 128 + 2 * c2] = m0;
        of[(size_t)v * 128 + 2 * c2 + 1] = m1;
    }
}

// ---------- launch ----------
extern "C" void kernel_launch(void* const* d_in, const int* in_sizes, int n_in,
                              void* d_out, int out_size, void* d_ws, size_t ws_size,
                              hipStream_t stream) {
    const void* pts = d_in[0];
    const void* W1 = d_in[1];
    const void* b1 = d_in[2];
    const void* g1 = d_in[3];
    const void* be1 = d_in[4];
    const void* W2 = d_in[5];
    const void* b2 = d_in[6];
    const void* g2 = d_in[7];
    const void* be2 = d_in[8];
    const void* W3 = d_in[9];
    const void* b3 = d_in[10];

    char* ws = (char*)d_ws;
    size_t off = 0;
    auto alloc = [&](size_t bytes) -> size_t {
        size_t o = off;
        off = (off + bytes + 255) & ~(size_t)255;
        return o;
    };
    size_t zstart = off;
    u32* occ = (u32*)(ws + alloc((size_t)NW * 4));
    u32* slotctr = (u32*)(ws + alloc((size_t)MAXV * 4));
    size_t zend = off;
    u32* wordbase = (u32*)(ws + alloc((size_t)NW * 4));  // memset 0xFF
    u32* voxbase = (u32*)(ws + alloc((size_t)MAXV * 4));
    u32* bsums = (u32*)(ws + alloc((size_t)SNB * 4));
    u32* vbsums = (u32*)(ws + alloc((size_t)VB * 4));
    int* firstkey = (int*)(ws + alloc(256));
    u32* dflag = (u32*)(ws + alloc(256));
    u32* nkept = (u32*)(ws + alloc(256));
    float* mu1 = (float*)(ws + alloc(256));
    float* rs1 = (float*)(ws + alloc(256));
    float* z2z = (float*)(ws + alloc(256));
    double* part1 = (double*)(ws + alloc((size_t)S1B * 128 * 8));
    double* part2c = (double*)(ws + alloc((size_t)64 * SZSEG * 2 * 8));
    float4* slotted = (float4*)(ws + alloc((size_t)NTOT * 16));
    float4* cpt = (float4*)(ws + alloc((size_t)PCAP * 16));
    u16* z2b = (u16*)(ws + alloc((size_t)64 * PCAP * 2));
    u16* out3b = (u16*)(ws + alloc((size_t)PCAP * 128 * 2));
    if (off > ws_size) return; // workspace too small

    hipMemsetAsync(ws + zstart, 0, zend - zstart, stream);
    hipMemsetAsync(wordbase, 0xFF, (size_t)NW * 4, stream);

    k_detect<<<1, 256, 0, stream>>>(pts, dflag, firstkey);
    k_hist<<<(NPTS + 255) / 256, 256, 0, stream>>>(pts, dflag, occ);
    k_scan1<<<SNB, 256, 0, stream>>>(occ, bsums, firstkey);
    k_scan3<<<SNB, 256, 0, stream>>>(occ, bsums, firstkey, dflag, wordbase, d_out);
    k_gather<<<(NPTS + 255) / 256, 256, 0, stream>>>(pts, occ, wordbase, dflag, slotctr, slotted);
    k_vox1<<<VB, 256, 0, stream>>>(slotctr, vbsums);
    k_vox3<<<VB, 256, 0, stream>>>(slotctr, vbsums, voxbase, slotted, cpt, nkept);
    k_stats1<<<S1B, 256, 0, stream>>>(W1, b1, dflag, nkept, cpt, part1);
    k_fin1<<<1, 256, 0, stream>>>(b1, g1, be1, W2, b2, dflag, nkept, part1, mu1, rs1, z2z);
    k_passZ2<<<(PCAP / 512) * 2, 256, 0, stream>>>(W1, b1, g1, be1, W2, b2, dflag, nkept, mu1, rs1, cpt, z2b);
    k_statsZ<<<64 * SZSEG, 256, 0, stream>>>(z2b, nkept, part2c);
    k_passOut<<<(PCAP / 256) * 4, 256, 0, stream>>>(W3, b3, g2, be2, dflag, nkept, part2c, z2z, z2b, out3b);
    k_maxOut<<<(64 * MAXV) / 256, 256, 0, stream>>>(out3b, slotctr, voxbase, dflag, d_out);
}